// Round 9
// baseline (1873.341 us; speedup 1.0000x reference)
//
#include <hip/hip_runtime.h>
#include <hip/hip_bf16.h>

// CTRNN: T=512, B=64, I=512, H=1024 — single persistent kernel.
// 64 blocks = 4 batch-groups (r, 16 rows) x 16 col-groups (g, 64 cols).
//   - W_hh slice (64 cols x 1024 K) pinned in LDS (128 KB), K-major MFMA frags.
//   - W_in slice (64 cols x 512 K) pinned in REGISTERS (16 short8/lane, K-split/wave).
//   - Per step: xp = x[t]·W_in^T computed into acc BEFORE the poll (bubble fill),
//     then h_t·W_hh^T accumulates on top; 4-wave K-partials reduced via LDS.
//   - h exchanged through fragment-tiled bf16 ring, flag protocol proven in r2/4/8:
//     publish -> vmcnt(0) -> barrier -> flag; consumer polls its 4 producers.
//   - out[t] = h_{t+1} written once (no xp staging round-trip); h_last appended.

typedef __attribute__((ext_vector_type(8))) short short8;
typedef __attribute__((ext_vector_type(4))) float f32x4;
typedef unsigned long long ull;

#define TT 512
#define BB 64
#define II 512
#define HH 1024

__device__ __forceinline__ short f2bf(float f) {
  unsigned u = __builtin_bit_cast(unsigned, f);
  u += 0x7fffu + ((u >> 16) & 1u);   // RNE
  return (short)(u >> 16);
}

__device__ __forceinline__ short8 pack8(const float* p) {
  short8 s;
  s[0] = f2bf(p[0]); s[1] = f2bf(p[1]); s[2] = f2bf(p[2]); s[3] = f2bf(p[3]);
  s[4] = f2bf(p[4]); s[5] = f2bf(p[5]); s[6] = f2bf(p[6]); s[7] = f2bf(p[7]);
  return s;
}

// ---------------- persistent fused kernel: 64 blocks x 256 thr
__global__ __launch_bounds__(256, 1) void rnn_persist(
    const float* __restrict__ x, const float* __restrict__ h0,
    const float* __restrict__ Win, const float* __restrict__ bin,
    const float* __restrict__ Whh, const float* __restrict__ bhh,
    float* __restrict__ out, short* __restrict__ ring0,
    short* __restrict__ ring1, int* __restrict__ flags) {
  __shared__ short Wl[64 * 1024];   // W_hh frag (kc,n) at (kc*64+n)*8 shorts, 128 KB
  __shared__ float Pr[4 * 16 * 68]; // per-wave K-partials, stride 68 (anti-conflict)

  const int bid = blockIdx.x;
  const int r = bid & 3, g = bid >> 2;
  const int tid = threadIdx.x;
  const int l = tid & 63, w = tid >> 6;
  const int lr = l & 15, lg = l >> 4;
  const int n0 = g * 64;

  // ---- stage W_hh rows (output cols) [64g, 64g+64), K-major bf16 fragments, LDS
  for (int j = 0; j < 32; ++j) {
    int c = j * 256 + tid;           // c = n*128 + kc
    int kc = c & 127, n = c >> 7;
    const float* src = Whh + (size_t)(n0 + n) * HH + kc * 8;
    float4 v0 = *(const float4*)src;
    float4 v1 = *(const float4*)(src + 4);
    short* d = Wl + (((size_t)kc * 64 + n) << 3);
    d[0] = f2bf(v0.x); d[1] = f2bf(v0.y); d[2] = f2bf(v0.z); d[3] = f2bf(v0.w);
    d[4] = f2bf(v1.x); d[5] = f2bf(v1.y); d[6] = f2bf(v1.z); d[7] = f2bf(v1.w);
  }

  // ---- stage W_in B-fragments in registers: wave w owns k in [128w, 128w+128)
  // frag (nt, kc): col n = n0+nt*16+lr, k = 128w + kc*32 + lg*8
  short8 wf[4][4];
  #pragma unroll
  for (int nt = 0; nt < 4; ++nt) {
    #pragma unroll
    for (int kc = 0; kc < 4; ++kc) {
      const float* src = Win + (size_t)(n0 + nt * 16 + lr) * II + w * 128 + kc * 32 + lg * 8;
      float tmp[8];
      *(float4*)&tmp[0] = *(const float4*)src;
      *(float4*)&tmp[4] = *(const float4*)(src + 4);
      wf[nt][kc] = pack8(tmp);
    }
  }

  // ---- epilogue thread tile: row brow (0..15), cols c0..c0+3 within block chunk
  const int brow = tid >> 4;
  const int c0 = (tid & 15) * 4;
  const size_t oidx = (size_t)(16 * r + brow) * HH + n0 + c0;
  const size_t ringoff =
      (((size_t)(r * 128 + 8 * g + (c0 >> 3)) * 16 + brow) << 3) + (c0 & 7);

  // bias (b_in + b_hh) for this thread's 4 cols
  f32x4 bias;
  #pragma unroll
  for (int k = 0; k < 4; ++k)
    bias[k] = bin[n0 + c0 + k] + bhh[n0 + c0 + k];

  // ---- init ring0 from h0; carry own h in register
  f32x4 hpv;
  {
    float4 v = *(const float4*)(h0 + oidx);
    hpv[0] = v.x; hpv[1] = v.y; hpv[2] = v.z; hpv[3] = v.w;
    ull u = (ull)(unsigned short)f2bf(v.x)
          | ((ull)(unsigned short)f2bf(v.y) << 16)
          | ((ull)(unsigned short)f2bf(v.z) << 32)
          | ((ull)(unsigned short)f2bf(v.w) << 48);
    __hip_atomic_store((ull*)(ring0 + ringoff), u,
                       __ATOMIC_RELAXED, __HIP_MEMORY_SCOPE_AGENT);
  }

  // ---- stage x[0] A-fragment floats (row = 16r+lr, k = 128w + kc*32 + lg*8)
  float xs[4][8];
  {
    const float* xb = x + ((size_t)(16 * r + lr)) * II + w * 128 + lg * 8;
    #pragma unroll
    for (int kc = 0; kc < 4; ++kc) {
      *(float4*)&xs[kc][0] = *(const float4*)(xb + kc * 32);
      *(float4*)&xs[kc][4] = *(const float4*)(xb + kc * 32 + 4);
    }
  }

  __syncthreads();  // W_hh LDS staged; vmcnt drained (ring init at coherence point)
  if (tid == 0)
    __hip_atomic_store(&flags[bid], 1, __ATOMIC_RELAXED, __HIP_MEMORY_SCOPE_AGENT);

  // wave w consumes kc in [32w, 32w+32) -> producer blocks bid' = 16w + 4(l&3) + r
  const int fidx = 16 * w + 4 * (l & 3) + r;
  const short* bW = Wl + ((((size_t)(32 * w + lg)) * 64 + lr) << 3);
  const size_t abase = ((((size_t)(r * 128 + 32 * w + lg)) * 16 + lr) << 3);

  for (int t = 0; t < TT; ++t) {
    short* rc = (t & 1) ? ring1 : ring0;
    short* rn = (t & 1) ? ring0 : ring1;
    float* outt = out + (size_t)t * (BB * HH);

    // 0. bubble work: convert x stage to bf16 frags, run 16 xp MFMAs into acc
    f32x4 acc[4];
    acc[0] = acc[1] = acc[2] = acc[3] = (f32x4){0.f, 0.f, 0.f, 0.f};
    #pragma unroll
    for (int kc = 0; kc < 4; ++kc) {
      short8 xa = pack8(xs[kc]);
      acc[0] = __builtin_amdgcn_mfma_f32_16x16x32_bf16(xa, wf[0][kc], acc[0], 0, 0, 0);
      acc[1] = __builtin_amdgcn_mfma_f32_16x16x32_bf16(xa, wf[1][kc], acc[1], 0, 0, 0);
      acc[2] = __builtin_amdgcn_mfma_f32_16x16x32_bf16(xa, wf[2][kc], acc[2], 0, 0, 0);
      acc[3] = __builtin_amdgcn_mfma_f32_16x16x32_bf16(xa, wf[3][kc], acc[3], 0, 0, 0);
    }

    // 1. wait for this wave's 4 producers to have published h_t
    {
      int target = t + 1;
      while (!__all(__hip_atomic_load(&flags[fidx], __ATOMIC_RELAXED,
                                      __HIP_MEMORY_SCOPE_AGENT) >= target))
        __builtin_amdgcn_s_sleep(1);
    }

    // 2. coherent A loads of this wave's K-slice (kc = 32w+lg+4i)
    const short* ar = rc + abase;
    const short* ar2 = ar + 2048;  // +4096 bytes
    int4 fa[8];
#define LDA(I, BASE, OFF) \
    asm volatile("global_load_dwordx4 %0, %1, off offset:%2 sc0 sc1" \
                 : "=v"(fa[I]) : "v"(BASE), "n"(OFF))
    LDA(0, ar, 0); LDA(1, ar, 1024); LDA(2, ar, 2048); LDA(3, ar, 3072);
    LDA(4, ar2, 0); LDA(5, ar2, 1024); LDA(6, ar2, 2048); LDA(7, ar2, 3072);
#undef LDA
    asm volatile("s_waitcnt vmcnt(0)" ::: "memory");
    __builtin_amdgcn_sched_barrier(0);

    // 3. W_hh MFMAs accumulate on top of xp
    #pragma unroll
    for (int i = 0; i < 8; ++i) {
      short8 a = __builtin_bit_cast(short8, fa[i]);
      acc[0] = __builtin_amdgcn_mfma_f32_16x16x32_bf16(
          a, *(const short8*)(bW + i * 2048 + 0),   acc[0], 0, 0, 0);
      acc[1] = __builtin_amdgcn_mfma_f32_16x16x32_bf16(
          a, *(const short8*)(bW + i * 2048 + 128), acc[1], 0, 0, 0);
      acc[2] = __builtin_amdgcn_mfma_f32_16x16x32_bf16(
          a, *(const short8*)(bW + i * 2048 + 256), acc[2], 0, 0, 0);
      acc[3] = __builtin_amdgcn_mfma_f32_16x16x32_bf16(
          a, *(const short8*)(bW + i * 2048 + 384), acc[3], 0, 0, 0);
    }

    // 4. publish K-partials (xp + whh): D row = lg*4+jj (batch), col = nt*16+lr
    float* pw = Pr + w * 1088;
    #pragma unroll
    for (int nt = 0; nt < 4; ++nt) {
      #pragma unroll
      for (int jj = 0; jj < 4; ++jj)
        pw[(lg * 4 + jj) * 68 + nt * 16 + lr] = acc[nt][jj];
    }
    __syncthreads();

    // 5. reduce 4 K-partials + bias + sigmoid update (hpv carried in regs)
    const float* pb = Pr + brow * 68 + c0;
    f32x4 s = *(const f32x4*)(pb)
            + *(const f32x4*)(pb + 1088)
            + *(const f32x4*)(pb + 2176)
            + *(const f32x4*)(pb + 3264);
    f32x4 hn;
    #pragma unroll
    for (int k = 0; k < 4; ++k) {
      float pre = s[k] + bias[k];
      float sg = 1.f / (1.f + __expf(-pre));
      hn[k] = 0.8f * hpv[k] + 0.2f * sg;  // 1-ALPHA, ALPHA, GAIN=1
    }

    // 6. publish h_{t+1} to the ring (one 8B relaxed-agent store per thread)
    {
      ull u = (ull)(unsigned short)f2bf(hn[0])
            | ((ull)(unsigned short)f2bf(hn[1]) << 16)
            | ((ull)(unsigned short)f2bf(hn[2]) << 32)
            | ((ull)(unsigned short)f2bf(hn[3]) << 48);
      __hip_atomic_store((ull*)(rn + ringoff), u,
                         __ATOMIC_RELAXED, __HIP_MEMORY_SCOPE_AGENT);
    }
    // 7. drain ring stores, block barrier (also Pr reuse guard), raise flag
    asm volatile("s_waitcnt vmcnt(0)" ::: "memory");
    __syncthreads();
    if (tid == 0)
      __hip_atomic_store(&flags[bid], t + 2, __ATOMIC_RELAXED, __HIP_MEMORY_SCOPE_AGENT);

    // 8. non-critical tail: write h_{t+1} to out, prefetch x[t+1], carry hn
    *(float4*)(outt + oidx) = *(float4*)&hn;
    if (t == TT - 1) {
      *(float4*)(out + (size_t)TT * BB * HH + oidx) = *(float4*)&hn;
    } else {
      const float* xb = x + ((size_t)(t + 1) * BB + 16 * r + lr) * II + w * 128 + lg * 8;
      #pragma unroll
      for (int kc = 0; kc < 4; ++kc) {
        *(float4*)&xs[kc][0] = *(const float4*)(xb + kc * 32);
        *(float4*)&xs[kc][4] = *(const float4*)(xb + kc * 32 + 4);
      }
    }
    hpv = hn;
  }
}

extern "C" void kernel_launch(void* const* d_in, const int* in_sizes, int n_in,
                              void* d_out, int out_size, void* d_ws, size_t ws_size,
                              hipStream_t stream) {
  const float* x   = (const float*)d_in[0];
  const float* h0  = (const float*)d_in[1];
  const float* Win = (const float*)d_in[2];
  const float* bin = (const float*)d_in[3];
  const float* Whh = (const float*)d_in[4];
  const float* bhh = (const float*)d_in[5];
  float* out = (float*)d_out;

  int* flags = (int*)d_ws;                       // 64 ints (256 B)
  short* ring0 = (short*)((char*)d_ws + 256);    // 128 KB
  short* ring1 = ring0 + BB * HH;                // 128 KB (total 262,400 B, proven)

  hipMemsetAsync(d_ws, 0, 256, stream);
  rnn_persist<<<dim3(64), 256, 0, stream>>>(x, h0, Win, bin, Whh, bhh,
                                            out, ring0, ring1, flags);
}

// Round 10
// 1718.132 us; speedup vs baseline: 1.0903x; 1.0903x over previous
//
#include <hip/hip_runtime.h>
#include <hip/hip_bf16.h>

// CTRNN: T=512, B=64, I=512, H=1024 — single persistent kernel.
// 64 blocks = 4 batch-groups (r, 16 rows) x 16 col-groups (g, 64 cols).
//   - W_hh slice (64 cols x 1024 K) pinned in LDS (128 KB), K-major MFMA frags.
//   - W_in slice pinned in REGISTERS (16 short8/lane, K-split per wave).
//   - xp for step t+1 computed in the TAIL of step t, BETWEEN the ring-store
//     issue and the vmcnt(0) drain: the pack+MFMA work (no memory ops) hides
//     under the ~0.5-0.7us store-ack wait (round-9 lesson: pre-poll work is
//     NOT hidden; the only real bubble is the drain).
//   - x[t+1] loaded a FULL step ahead (issued after flag raise of step t-1).
//   - h exchanged via fragment-tiled bf16 ring + flag protocol (proven r2/4/8/9):
//     publish -> [xp work] -> vmcnt(0) -> barrier -> flag; consumer polls 4 producers.

typedef __attribute__((ext_vector_type(8))) short short8;
typedef __attribute__((ext_vector_type(4))) float f32x4;
typedef unsigned long long ull;

#define TT 512
#define BB 64
#define II 512
#define HH 1024

__device__ __forceinline__ short f2bf(float f) {
  unsigned u = __builtin_bit_cast(unsigned, f);
  u += 0x7fffu + ((u >> 16) & 1u);   // RNE
  return (short)(u >> 16);
}

__device__ __forceinline__ short8 pack8(const float* p) {
  short8 s;
  s[0] = f2bf(p[0]); s[1] = f2bf(p[1]); s[2] = f2bf(p[2]); s[3] = f2bf(p[3]);
  s[4] = f2bf(p[4]); s[5] = f2bf(p[5]); s[6] = f2bf(p[6]); s[7] = f2bf(p[7]);
  return s;
}

// ---------------- persistent fused kernel: 64 blocks x 256 thr
__global__ __launch_bounds__(256, 1) void rnn_persist(
    const float* __restrict__ x, const float* __restrict__ h0,
    const float* __restrict__ Win, const float* __restrict__ bin,
    const float* __restrict__ Whh, const float* __restrict__ bhh,
    float* __restrict__ out, short* __restrict__ ring0,
    short* __restrict__ ring1, int* __restrict__ flags) {
  __shared__ short Wl[64 * 1024];   // W_hh frag (kc,n) at (kc*64+n)*8 shorts, 128 KB
  __shared__ float Pr[4 * 16 * 68]; // per-wave K-partials, stride 68 (anti-conflict)

  const int bid = blockIdx.x;
  const int r = bid & 3, g = bid >> 2;
  const int tid = threadIdx.x;
  const int l = tid & 63, w = tid >> 6;
  const int lr = l & 15, lg = l >> 4;
  const int n0 = g * 64;

  // ---- stage W_hh rows (output cols) [64g, 64g+64), K-major bf16 fragments, LDS
  for (int j = 0; j < 32; ++j) {
    int c = j * 256 + tid;           // c = n*128 + kc
    int kc = c & 127, n = c >> 7;
    const float* src = Whh + (size_t)(n0 + n) * HH + kc * 8;
    float4 v0 = *(const float4*)src;
    float4 v1 = *(const float4*)(src + 4);
    short* d = Wl + (((size_t)kc * 64 + n) << 3);
    d[0] = f2bf(v0.x); d[1] = f2bf(v0.y); d[2] = f2bf(v0.z); d[3] = f2bf(v0.w);
    d[4] = f2bf(v1.x); d[5] = f2bf(v1.y); d[6] = f2bf(v1.z); d[7] = f2bf(v1.w);
  }

  // ---- stage W_in B-fragments in registers: wave w owns k in [128w, 128w+128)
  short8 wf[4][4];
  #pragma unroll
  for (int nt = 0; nt < 4; ++nt) {
    #pragma unroll
    for (int kc = 0; kc < 4; ++kc) {
      const float* src = Win + (size_t)(n0 + nt * 16 + lr) * II + w * 128 + kc * 32 + lg * 8;
      float tmp[8];
      *(float4*)&tmp[0] = *(const float4*)src;
      *(float4*)&tmp[4] = *(const float4*)(src + 4);
      wf[nt][kc] = pack8(tmp);
    }
  }

  // ---- epilogue thread tile: row brow (0..15), cols c0..c0+3 within block chunk
  const int brow = tid >> 4;
  const int c0 = (tid & 15) * 4;
  const size_t oidx = (size_t)(16 * r + brow) * HH + n0 + c0;
  const size_t ringoff =
      (((size_t)(r * 128 + 8 * g + (c0 >> 3)) * 16 + brow) << 3) + (c0 & 7);

  // bias (b_in + b_hh) for this thread's 4 cols
  f32x4 bias;
  #pragma unroll
  for (int k = 0; k < 4; ++k)
    bias[k] = bin[n0 + c0 + k] + bhh[n0 + c0 + k];

  // ---- init ring0 from h0; carry own h in register
  f32x4 hpv;
  {
    float4 v = *(const float4*)(h0 + oidx);
    hpv[0] = v.x; hpv[1] = v.y; hpv[2] = v.z; hpv[3] = v.w;
    ull u = (ull)(unsigned short)f2bf(v.x)
          | ((ull)(unsigned short)f2bf(v.y) << 16)
          | ((ull)(unsigned short)f2bf(v.z) << 32)
          | ((ull)(unsigned short)f2bf(v.w) << 48);
    __hip_atomic_store((ull*)(ring0 + ringoff), u,
                       __ATOMIC_RELAXED, __HIP_MEMORY_SCOPE_AGENT);
  }

  // ---- x stage: row = 16r+lr, k = 128w + kc*32 + lg*8
  const float* xbase = x + ((size_t)(16 * r + lr)) * II + w * 128 + lg * 8;
  float xs[4][8];
  #pragma unroll
  for (int kc = 0; kc < 4; ++kc) {       // x[0]
    *(float4*)&xs[kc][0] = *(const float4*)(xbase + kc * 32);
    *(float4*)&xs[kc][4] = *(const float4*)(xbase + kc * 32 + 4);
  }

  // pre-compute xp for t=0 (waits x[0] loads; once, outside the loop)
  f32x4 acc[4];
  acc[0] = acc[1] = acc[2] = acc[3] = (f32x4){0.f, 0.f, 0.f, 0.f};
  #pragma unroll
  for (int kc = 0; kc < 4; ++kc) {
    short8 xa = pack8(xs[kc]);
    acc[0] = __builtin_amdgcn_mfma_f32_16x16x32_bf16(xa, wf[0][kc], acc[0], 0, 0, 0);
    acc[1] = __builtin_amdgcn_mfma_f32_16x16x32_bf16(xa, wf[1][kc], acc[1], 0, 0, 0);
    acc[2] = __builtin_amdgcn_mfma_f32_16x16x32_bf16(xa, wf[2][kc], acc[2], 0, 0, 0);
    acc[3] = __builtin_amdgcn_mfma_f32_16x16x32_bf16(xa, wf[3][kc], acc[3], 0, 0, 0);
  }

  __syncthreads();  // W_hh LDS staged; vmcnt drained (ring init at coherence point)
  if (tid == 0)
    __hip_atomic_store(&flags[bid], 1, __ATOMIC_RELAXED, __HIP_MEMORY_SCOPE_AGENT);

  // prefetch x[1] (full-step-ahead cover)
  #pragma unroll
  for (int kc = 0; kc < 4; ++kc) {
    *(float4*)&xs[kc][0] = *(const float4*)(xbase + (size_t)BB * II + kc * 32);
    *(float4*)&xs[kc][4] = *(const float4*)(xbase + (size_t)BB * II + kc * 32 + 4);
  }

  // wave w consumes kc in [32w, 32w+32) -> producer blocks bid' = 16w + 4(l&3) + r
  const int fidx = 16 * w + 4 * (l & 3) + r;
  const short* bW = Wl + ((((size_t)(32 * w + lg)) * 64 + lr) << 3);
  const size_t abase = ((((size_t)(r * 128 + 32 * w + lg)) * 16 + lr) << 3);

  for (int t = 0; t < TT; ++t) {
    short* rc = (t & 1) ? ring1 : ring0;
    short* rn = (t & 1) ? ring0 : ring1;
    float* outt = out + (size_t)t * (BB * HH);

    // 1. wait for this wave's 4 producers to have published h_t
    {
      int target = t + 1;
      while (!__all(__hip_atomic_load(&flags[fidx], __ATOMIC_RELAXED,
                                      __HIP_MEMORY_SCOPE_AGENT) >= target))
        __builtin_amdgcn_s_sleep(1);
    }

    // 2. coherent A loads of this wave's K-slice (kc = 32w+lg+4i)
    const short* ar = rc + abase;
    const short* ar2 = ar + 2048;  // +4096 bytes
    int4 fa[8];
#define LDA(I, BASE, OFF) \
    asm volatile("global_load_dwordx4 %0, %1, off offset:%2 sc0 sc1" \
                 : "=v"(fa[I]) : "v"(BASE), "n"(OFF))
    LDA(0, ar, 0); LDA(1, ar, 1024); LDA(2, ar, 2048); LDA(3, ar, 3072);
    LDA(4, ar2, 0); LDA(5, ar2, 1024); LDA(6, ar2, 2048); LDA(7, ar2, 3072);
#undef LDA
    asm volatile("s_waitcnt vmcnt(0)" ::: "memory");
    __builtin_amdgcn_sched_barrier(0);

    // 3. W_hh MFMAs accumulate on top of xp (acc holds xp[t])
    #pragma unroll
    for (int i = 0; i < 8; ++i) {
      short8 a = __builtin_bit_cast(short8, fa[i]);
      acc[0] = __builtin_amdgcn_mfma_f32_16x16x32_bf16(
          a, *(const short8*)(bW + i * 2048 + 0),   acc[0], 0, 0, 0);
      acc[1] = __builtin_amdgcn_mfma_f32_16x16x32_bf16(
          a, *(const short8*)(bW + i * 2048 + 128), acc[1], 0, 0, 0);
      acc[2] = __builtin_amdgcn_mfma_f32_16x16x32_bf16(
          a, *(const short8*)(bW + i * 2048 + 256), acc[2], 0, 0, 0);
      acc[3] = __builtin_amdgcn_mfma_f32_16x16x32_bf16(
          a, *(const short8*)(bW + i * 2048 + 384), acc[3], 0, 0, 0);
    }

    // 4. publish K-partials (xp + whh): D row = lg*4+jj (batch), col = nt*16+lr
    float* pw = Pr + w * 1088;
    #pragma unroll
    for (int nt = 0; nt < 4; ++nt) {
      #pragma unroll
      for (int jj = 0; jj < 4; ++jj)
        pw[(lg * 4 + jj) * 68 + nt * 16 + lr] = acc[nt][jj];
    }
    __syncthreads();

    // 5. reduce 4 K-partials + bias + sigmoid update (hpv carried in regs)
    const float* pb = Pr + brow * 68 + c0;
    f32x4 s = *(const f32x4*)(pb)
            + *(const f32x4*)(pb + 1088)
            + *(const f32x4*)(pb + 2176)
            + *(const f32x4*)(pb + 3264);
    f32x4 hn;
    #pragma unroll
    for (int k = 0; k < 4; ++k) {
      float pre = s[k] + bias[k];
      float sg = 1.f / (1.f + __expf(-pre));
      hn[k] = 0.8f * hpv[k] + 0.2f * sg;  // 1-ALPHA, ALPHA, GAIN=1
    }

    // 6. publish h_{t+1} to the ring + out[t] (fire-and-forget issues)
    {
      ull u = (ull)(unsigned short)f2bf(hn[0])
            | ((ull)(unsigned short)f2bf(hn[1]) << 16)
            | ((ull)(unsigned short)f2bf(hn[2]) << 32)
            | ((ull)(unsigned short)f2bf(hn[3]) << 48);
      __hip_atomic_store((ull*)(rn + ringoff), u,
                         __ATOMIC_RELAXED, __HIP_MEMORY_SCOPE_AGENT);
    }
    *(float4*)(outt + oidx) = *(float4*)&hn;

    // 6b. xp for step t+1 — pure reg VALU+MFMA, hides under the store-ack drain
    if (t < TT - 1) {
      acc[0] = acc[1] = acc[2] = acc[3] = (f32x4){0.f, 0.f, 0.f, 0.f};
      #pragma unroll
      for (int kc = 0; kc < 4; ++kc) {
        short8 xa = pack8(xs[kc]);   // xs holds x[t+1]
        acc[0] = __builtin_amdgcn_mfma_f32_16x16x32_bf16(xa, wf[0][kc], acc[0], 0, 0, 0);
        acc[1] = __builtin_amdgcn_mfma_f32_16x16x32_bf16(xa, wf[1][kc], acc[1], 0, 0, 0);
        acc[2] = __builtin_amdgcn_mfma_f32_16x16x32_bf16(xa, wf[2][kc], acc[2], 0, 0, 0);
        acc[3] = __builtin_amdgcn_mfma_f32_16x16x32_bf16(xa, wf[3][kc], acc[3], 0, 0, 0);
      }
    }

    // 7. drain ring stores, block barrier (also Pr reuse guard), raise flag
    asm volatile("s_waitcnt vmcnt(0)" ::: "memory");
    __syncthreads();
    if (tid == 0)
      __hip_atomic_store(&flags[bid], t + 2, __ATOMIC_RELAXED, __HIP_MEMORY_SCOPE_AGENT);

    // 8. non-critical tail: h_last write, prefetch x[t+2], carry hn
    if (t == TT - 1) {
      *(float4*)(out + (size_t)TT * BB * HH + oidx) = *(float4*)&hn;
    } else if (t + 2 < TT) {
      const float* xb = xbase + (size_t)(t + 2) * (BB * II);
      #pragma unroll
      for (int kc = 0; kc < 4; ++kc) {
        *(float4*)&xs[kc][0] = *(const float4*)(xb + kc * 32);
        *(float4*)&xs[kc][4] = *(const float4*)(xb + kc * 32 + 4);
      }
    }
    hpv = hn;
  }
}

extern "C" void kernel_launch(void* const* d_in, const int* in_sizes, int n_in,
                              void* d_out, int out_size, void* d_ws, size_t ws_size,
                              hipStream_t stream) {
  const float* x   = (const float*)d_in[0];
  const float* h0  = (const float*)d_in[1];
  const float* Win = (const float*)d_in[2];
  const float* bin = (const float*)d_in[3];
  const float* Whh = (const float*)d_in[4];
  const float* bhh = (const float*)d_in[5];
  float* out = (float*)d_out;

  int* flags = (int*)d_ws;                       // 64 ints (256 B)
  short* ring0 = (short*)((char*)d_ws + 256);    // 128 KB
  short* ring1 = ring0 + BB * HH;                // 128 KB (total 262,400 B, proven)

  hipMemsetAsync(d_ws, 0, 256, stream);
  rnn_persist<<<dim3(64), 256, 0, stream>>>(x, h0, Win, bin, Whh, bhh,
                                            out, ring0, ring1, flags);
}